// Round 1
// 9817.667 us; speedup vs baseline: 1.0328x; 1.0328x over previous
//
#include <hip/hip_runtime.h>

typedef unsigned int u32;
typedef unsigned long long u64;
typedef float f32x2 __attribute__((ext_vector_type(2)));

#define N_PTS 16384
#define N_S   8192
#define NB    10
#define CHID  64
#define COUT  128
#define R2    0.0625f
#define NCELL 4096

// ======================= sort: morton counting sort =======================
__global__ void zero_hist(int* __restrict__ hist) {
  hist[blockIdx.x * 256 + threadIdx.x] = 0;
}

__device__ __forceinline__ u32 spread3(u32 v) {  // 4 bits -> every 3rd bit
  return (v & 1u) | ((v & 2u) << 2) | ((v & 4u) << 4) | ((v & 8u) << 6);
}

__global__ void cell_kernel(const float* __restrict__ pos, int* __restrict__ cellid,
                            int* __restrict__ hist) {
  int i = blockIdx.x * 256 + threadIdx.x;
  float x = pos[3 * i], y = pos[3 * i + 1], z = pos[3 * i + 2];
  u32 ix = (u32)(x * 16.0f); if (ix > 15u) ix = 15u;
  u32 iy = (u32)(y * 16.0f); if (iy > 15u) iy = 15u;
  u32 iz = (u32)(z * 16.0f); if (iz > 15u) iz = 15u;
  u32 c = spread3(ix) | (spread3(iy) << 1) | (spread3(iz) << 2);
  cellid[i] = (int)c;
  atomicAdd(&hist[c], 1);
}

__global__ __launch_bounds__(1024) void scan_kernel(const int* __restrict__ hist,
                                                    int* __restrict__ base) {
  __shared__ int sp[1024];
  int t = threadIdx.x;
  int h0 = hist[4 * t], h1 = hist[4 * t + 1], h2 = hist[4 * t + 2], h3 = hist[4 * t + 3];
  int s = h0 + h1 + h2 + h3;
  int acc = s;
  sp[t] = s;
  __syncthreads();
  for (int off = 1; off < 1024; off <<= 1) {
    int v = (t >= off) ? sp[t - off] : 0;
    __syncthreads();
    acc += v;
    sp[t] = acc;
    __syncthreads();
  }
  int excl = acc - s;
  base[4 * t + 0] = excl;
  base[4 * t + 1] = excl + h0;
  base[4 * t + 2] = excl + h0 + h1;
  base[4 * t + 3] = excl + h0 + h1 + h2;
}

__global__ void scatter_kernel(const float* __restrict__ pos, const int* __restrict__ cellid,
                               int* __restrict__ base, float* __restrict__ xs,
                               float* __restrict__ ys, float* __restrict__ zs,
                               int* __restrict__ oid) {
  int i = blockIdx.x * 256 + threadIdx.x;
  int c = cellid[i];
  int d = atomicAdd(&base[c], 1);
  xs[d] = pos[3 * i]; ys[d] = pos[3 * i + 1]; zs[d] = pos[3 * i + 2];
  oid[d] = i;
}

// ======================= FPS: R18 (from R16 @ 9.13 ms) ======================
// R18 theory: single-CU VALU-issue bound (CU VALUBusy ~70%). Cut body issue:
//  - packed f32 (v_pk_add/mul_f32) for dx/dy/dz/d2: 8 pk insts per point-PAIR
//    (identical IEEE RNE per op, same (dx2+dy2)+dz2 association, sub as x+(-c))
//  - x[16] in registers (8 f32x2) -> no global loads in body
//  - bbox in registers (lane-private constant; was LDS) -> -2 LDS reads/iter
//  - precomputed key low consts C_J=(16383-oid)<<14|sidx -> key = shr + lshl_or + max_f64
//  - y/z LDS pair-packed planes so packed operands are single ds_read_b64
// Unchanged: prune logic, DPP wave reduce, parity wkey forward, all-wave block
// reduce, exact-rounding semantics, key layout.
#define FPS_T 1024
#define PPT   16

#define PT_LIST(OP) OP(0) OP(1) OP(2) OP(3) OP(4) OP(5) OP(6) OP(7) \
                    OP(8) OP(9) OP(10) OP(11) OP(12) OP(13) OP(14) OP(15)
// OP(G, J0,J1,J2,J3, PA,PB): float4 group G covers points 4G..4G+3, pairs PA=2G, PB=2G+1
#define G4_LIST(OP) OP(0,0,1,2,3,0,1)   OP(1,4,5,6,7,2,3) \
                    OP(2,8,9,10,11,4,5) OP(3,12,13,14,15,6,7)
#define PR_LIST(OP) OP(0) OP(1) OP(2) OP(3) OP(4) OP(5) OP(6) OP(7)

// u64 max via positive-double max (keys < 2^60 -> exponent never all-ones, no
// NaN/inf patterns; positive doubles order == bit order).
__device__ __forceinline__ u64 u64fmax(u64 a, u64 b) {
  double ad = __longlong_as_double((long long)a);
  double bd = __longlong_as_double((long long)b);
  return (u64)(long long)__double_as_longlong(fmax(ad, bd));
}

template <int CTRL, int RM>
__device__ __forceinline__ u64 dppmax(u64 cur) {
  int slo = __builtin_amdgcn_update_dpp(0, (int)(u32)cur, CTRL, RM, 0xf, false);
  int shi = __builtin_amdgcn_update_dpp(0, (int)(u32)(cur >> 32), CTRL, RM, 0xf, false);
  u64 o = ((u64)(u32)shi << 32) | (u32)slo;
  return u64fmax(o, cur);
}

// packed 2xf32 ops (VOP3P, gfx90a+). IEEE RNE per element, no contraction
// possible (opaque asm), denorm mode identical to scalar VALU.
__device__ __forceinline__ f32x2 pk_add(f32x2 a, f32x2 b) {
  f32x2 d;
  asm("v_pk_add_f32 %0, %1, %2" : "=v"(d) : "v"(a), "v"(b));
  return d;
}
__device__ __forceinline__ f32x2 pk_mul(f32x2 a, f32x2 b) {
  f32x2 d;
  asm("v_pk_mul_f32 %0, %1, %2" : "=v"(d) : "v"(a), "v"(b));
  return d;
}

__global__ __launch_bounds__(FPS_T, 4)
void fps_kernel(const float* __restrict__ pos,
                const float* __restrict__ xs,
                const float* __restrict__ ys,
                const float* __restrict__ zs,
                const int* __restrict__ oidv,
                int* __restrict__ idx_out) {
  __shared__ f32x2 s_yp[(PPT / 2) * FPS_T];  // pair p -> (y_{2p}, y_{2p+1}): 64 KB
  __shared__ f32x2 s_zp[(PPT / 2) * FPS_T];  // pair p -> (z_{2p}, z_{2p+1}): 64 KB
  __shared__ u64   s_wkey[2][16];            // parity double-buffer
  const int t = threadIdx.x;
  const int wv = t >> 6;
  const int base0 = t * PPT;
  const float4* __restrict__ xv = (const float4*)(xs + base0);
  const float4* __restrict__ yv = (const float4*)(ys + base0);
  const float4* __restrict__ zv = (const float4*)(zs + base0);
  const int4*   __restrict__ ov = (const int4*)(oidv + base0);

  // ---- per-point register state: md, x pairs, key low-word constants
#define DECLP(J) float md##J;
  PT_LIST(DECLP)
#undef DECLP
#define DECLC(J) u32 C##J;
  PT_LIST(DECLC)
#undef DECLC
#define DECLX(P) f32x2 X##P;
  PR_LIST(DECLX)
#undef DECLX

  // lane-private chunk bbox lives in registers (constant after init)
  float bnx = 3.4e38f, bxx = -3.4e38f, bny = 3.4e38f, bxy = -3.4e38f,
        bnz = 3.4e38f, bxz = -3.4e38f;

#define INIT4(G, J0, J1, J2, J3, PA, PB) { \
    float4 vx = xv[G], vy = yv[G], vz = zv[G]; int4 vo = ov[G]; \
    md##J0 = 3.402823466e38f; md##J1 = 3.402823466e38f; \
    md##J2 = 3.402823466e38f; md##J3 = 3.402823466e38f; \
    X##PA.x = vx.x; X##PA.y = vx.y; X##PB.x = vx.z; X##PB.y = vx.w; \
    f32x2 y0; y0.x = vy.x; y0.y = vy.y; s_yp[PA * FPS_T + t] = y0; \
    f32x2 y1; y1.x = vy.z; y1.y = vy.w; s_yp[PB * FPS_T + t] = y1; \
    f32x2 z0; z0.x = vz.x; z0.y = vz.y; s_zp[PA * FPS_T + t] = z0; \
    f32x2 z1; z1.x = vz.z; z1.y = vz.w; s_zp[PB * FPS_T + t] = z1; \
    C##J0 = ((16383u - (u32)vo.x) << 14) | (u32)(base0 + J0); \
    C##J1 = ((16383u - (u32)vo.y) << 14) | (u32)(base0 + J1); \
    C##J2 = ((16383u - (u32)vo.z) << 14) | (u32)(base0 + J2); \
    C##J3 = ((16383u - (u32)vo.w) << 14) | (u32)(base0 + J3); \
    bnx = fminf(bnx, fminf(fminf(vx.x, vx.y), fminf(vx.z, vx.w))); \
    bxx = fmaxf(bxx, fmaxf(fmaxf(vx.x, vx.y), fmaxf(vx.z, vx.w))); \
    bny = fminf(bny, fminf(fminf(vy.x, vy.y), fminf(vy.z, vy.w))); \
    bxy = fmaxf(bxy, fmaxf(fmaxf(vy.x, vy.y), fmaxf(vy.z, vy.w))); \
    bnz = fminf(bnz, fminf(fminf(vz.x, vz.y), fminf(vz.z, vz.w))); \
    bxz = fmaxf(bxz, fmaxf(fmaxf(vz.x, vz.y), fmaxf(vz.z, vz.w))); }
  G4_LIST(INIT4)
#undef INIT4

  // key = md_bits<<28 | (16383-oid)<<14 | sidx (60 bits). md >= 0 -> float order
  // == bit order. Lex max == numpy argmax (max md, tie -> min oid); sidx trails.
  u64 ckey = 0;
  float cmaxf = 3.402823466e38f;        // forces all-active first iteration
  float cx = pos[0], cy = pos[1], cz = pos[2];
  if (t == 0) idx_out[0] = 0;
  __syncthreads();

  for (int k = 0; k < N_S - 1; ++k) {
    // ---- prune: bbox lower bound vs chunk max-min-dist. Skip-safe: if
    // 0.99*lb2 >= cmaxf no md in this chunk can decrease (1% margin >> fp32
    // rounding of 3-term sums) -> chunk state exactly unchanged.
    float dxl = fmaxf(fmaxf(bnx - cx, cx - bxx), 0.0f);
    float dyl = fmaxf(fmaxf(bny - cy, cy - bxy), 0.0f);
    float dzl = fmaxf(fmaxf(bnz - cz, cz - bxz), 0.0f);
    float lb2 = dxl * dxl + dyl * dyl + dzl * dzl;
    bool act = (0.99f * lb2 < cmaxf);
    const int p = k & 1;

    if (__ballot(act)) {
      if (act) {
        f32x2 ncx2; ncx2.x = -cx; ncx2.y = -cx;
        f32x2 ncy2; ncy2.x = -cy; ncy2.y = -cy;
        f32x2 ncz2; ncz2.x = -cz; ncz2.y = -cz;
        u64 bkA = 0, bkB = 0;   // even/odd accumulators: halves the dep chain
        // exact numpy arithmetic per element: x+(-c) == x-c (negation exact),
        // pk mul/add are per-op RNE, association (dx2+dy2)+dz2 preserved.
#define UPDP(P, J0, J1) { \
        f32x2 y2 = s_yp[P * FPS_T + t]; \
        f32x2 z2 = s_zp[P * FPS_T + t]; \
        f32x2 dx2 = pk_add(X##P, ncx2); \
        f32x2 dy2 = pk_add(y2, ncy2); \
        f32x2 dz2 = pk_add(z2, ncz2); \
        f32x2 sq = pk_add(pk_mul(dx2, dx2), pk_mul(dy2, dy2)); \
        f32x2 d2 = pk_add(sq, pk_mul(dz2, dz2)); \
        float m0 = fminf(md##J0, d2.x); md##J0 = m0; \
        u32 mb0 = __float_as_uint(m0); \
        bkA = u64fmax(bkA, ((u64)(mb0 >> 4) << 32) | ((mb0 << 28) | C##J0)); \
        float m1 = fminf(md##J1, d2.y); md##J1 = m1; \
        u32 mb1 = __float_as_uint(m1); \
        bkB = u64fmax(bkB, ((u64)(mb1 >> 4) << 32) | ((mb1 << 28) | C##J1)); }
        UPDP(0, 0, 1)  UPDP(1, 2, 3)  UPDP(2, 4, 5)  UPDP(3, 6, 7)
        UPDP(4, 8, 9)  UPDP(5, 10, 11) UPDP(6, 12, 13) UPDP(7, 14, 15)
#undef UPDP
        ckey = u64fmax(bkA, bkB);
        cmaxf = __uint_as_float((u32)(ckey >> 28));
      }
      // wave64 max via DPP (row_shr scan + row broadcasts): lane 63 = wave max.
      // Inactive lanes carry their old (still-valid) ckey.
      u64 wk = ckey;
      wk = dppmax<0x111, 0xf>(wk);   // row_shr:1
      wk = dppmax<0x112, 0xf>(wk);   // row_shr:2
      wk = dppmax<0x114, 0xf>(wk);   // row_shr:4
      wk = dppmax<0x118, 0xf>(wk);   // row_shr:8
      wk = dppmax<0x142, 0xa>(wk);   // row_bcast:15 -> rows 1,3
      wk = dppmax<0x143, 0xc>(wk);   // row_bcast:31 -> rows 2,3
      u32 wlo = (u32)__builtin_amdgcn_readlane((int)(u32)wk, 63);
      u32 whi = (u32)__builtin_amdgcn_readlane((int)(u32)(wk >> 32), 63);
      if ((t & 63) == 0) s_wkey[p][wv] = ((u64)whi << 32) | wlo;
    } else {
      // whole wave pruned: forward previous parity's winner entry. Single
      // writer per slot (this wave); [1-p] written at k-1, next overwrite at
      // k+1 -> always separated by the barrier below. No race.
      if ((t & 63) == 0) s_wkey[p][wv] = s_wkey[1 - p][wv];
    }
    __syncthreads();

    // ---- all waves redundantly reduce the 16 wave keys (row_ror, period-16)
    u64 gk = s_wkey[p][t & 15];
    gk = dppmax<0x121, 0xf>(gk);   // row_ror:1
    gk = dppmax<0x122, 0xf>(gk);   // row_ror:2
    gk = dppmax<0x124, 0xf>(gk);   // row_ror:4
    gk = dppmax<0x128, 0xf>(gk);   // row_ror:8
    u32 glo = (u32)__builtin_amdgcn_readfirstlane((int)(u32)gk);
    u32 ghi = (u32)__builtin_amdgcn_readfirstlane((int)(u32)(gk >> 32));
    u64 gmax = ((u64)ghi << 32) | glo;
    int sidx = (int)(gmax & 16383u);      // SGPR (from readfirstlane chain)
    if (t == 0) idx_out[k + 1] = 16383 - (int)((gmax >> 14) & 16383u);
    // next center: cx via scalar load from L1/L2-resident xs (sidx uniform);
    // cy,cz from the point's pair cell (uniform broadcast b64 reads + half sel).
    int tcell = sidx >> 4;
    int pj = (sidx >> 1) & 7;
    int half = sidx & 1;
    cx = xs[sidx];
    f32x2 vy = s_yp[pj * FPS_T + tcell];
    f32x2 vz = s_zp[pj * FPS_T + tcell];
    cy = half ? vy.y : vy.x;
    cz = half ? vz.y : vz.x;
  }
}

// ======================= zero the tail rows [N_S, N_PTS) =======================
__global__ void zero_tail(float4* __restrict__ outv, int count) {
  int i = blockIdx.x * blockDim.x + threadIdx.x;
  if (i < count) outv[i] = make_float4(0.f, 0.f, 0.f, 0.f);
}

// ======================= kNN: 8-way split + exact lex merge =======================
#define KNN_T  256   // 32 centers x 8 splits
#define KTILE  1024

__global__ __launch_bounds__(KNN_T) void knn_kernel(const float* __restrict__ pos,
                                                    const int* __restrict__ fps_idx,
                                                    int* __restrict__ src_out,
                                                    int* __restrict__ valid_out) {
  __shared__ float sx[KTILE], sy[KTILE], sz[KTILE];
  __shared__ float spd[32][8][NB];
  __shared__ int   spi[32][8][NB];
  const int t = threadIdx.x;
  const int sp = t >> 5;
  const int cl = t & 31;
  const int i = blockIdx.x * 32 + cl;
  const int ci = fps_idx[i];
  const float cx = pos[3 * ci], cy = pos[3 * ci + 1], cz = pos[3 * ci + 2];
  float nd[NB]; int ni[NB];
#pragma unroll
  for (int q = 0; q < NB; ++q) { nd[q] = 3.402823466e38f; ni[q] = 0x7fffffff; }

  for (int base = 0; base < N_PTS; base += KTILE) {
    __syncthreads();
    for (int j = t; j < KTILE; j += KNN_T) {
      int pnt = base + j;
      sx[j] = pos[3 * pnt]; sy[j] = pos[3 * pnt + 1]; sz[j] = pos[3 * pnt + 2];
    }
    __syncthreads();
    for (int j = sp; j < KTILE; j += 8) {
      float dx = __fsub_rn(cx, sx[j]);
      float dy = __fsub_rn(cy, sy[j]);
      float dz = __fsub_rn(cz, sz[j]);
      float d2 = __fadd_rn(__fadd_rn(__fmul_rn(dx, dx), __fmul_rn(dy, dy)), __fmul_rn(dz, dz));
      if (d2 < nd[NB - 1]) {
        float cd = d2; int cp = base + j;
#pragma unroll
        for (int q = 0; q < NB; ++q) {
          bool sw = (cd < nd[q]) || (cd == nd[q] && cp < ni[q]);
          if (sw) { float td = nd[q]; int tp = ni[q]; nd[q] = cd; ni[q] = cp; cd = td; cp = tp; }
        }
      }
    }
  }
#pragma unroll
  for (int q = 0; q < NB; ++q) { spd[cl][sp][q] = nd[q]; spi[cl][sp][q] = ni[q]; }
  __syncthreads();
  if (sp == 0) {
    int cur[8];
#pragma unroll
    for (int s = 0; s < 8; ++s) cur[s] = 0;
    int vb = 0;
    for (int q = 0; q < NB; ++q) {
      float bd = 3.402823466e38f; int bi = 0x7fffffff; int bsl = 0;
#pragma unroll
      for (int s = 0; s < 8; ++s) {
        float d = spd[cl][s][cur[s]]; int id = spi[cl][s][cur[s]];
        if (d < bd || (d == bd && id < bi)) { bd = d; bi = id; bsl = s; }
      }
#pragma unroll
      for (int s = 0; s < 8; ++s) cur[s] += (s == bsl) ? 1 : 0;
      src_out[i * NB + q] = bi;
      if (bd <= R2) vb |= (1 << q);
    }
    valid_out[i] = vb;
  }
}

// ======================= MLP + masked max-pool =======================
#define MLP_T 128

__global__ __launch_bounds__(MLP_T) void mlp_kernel(const float* __restrict__ pos,
                                                    const int* __restrict__ src,
                                                    const int* __restrict__ valid,
                                                    const float* __restrict__ W1,
                                                    const float* __restrict__ b1,
                                                    const float* __restrict__ W2,
                                                    const float* __restrict__ b2,
                                                    float* __restrict__ out) {
  __shared__ float sW2[CHID * COUT];
  __shared__ float sW1[3 * CHID];
  __shared__ float sb1[CHID];
  __shared__ float sh1[NB][CHID];
  __shared__ float srel[NB][3];
  __shared__ int   svalid;
  const int t = threadIdx.x;
  const int i = blockIdx.x;

  for (int e = t; e < CHID * COUT; e += MLP_T) sW2[e] = W2[e];
  for (int e = t; e < 3 * CHID; e += MLP_T) sW1[e] = W1[e];
  if (t < CHID) sb1[t] = b1[t];
  if (t < NB) {
    int s = src[i * NB + t];
    // NOTE: reference subtracts pos_i = pos[:s] (row i), NOT the sampled center
    srel[t][0] = pos[3 * s + 0] - pos[3 * i + 0];
    srel[t][1] = pos[3 * s + 1] - pos[3 * i + 1];
    srel[t][2] = pos[3 * s + 2] - pos[3 * i + 2];
  }
  if (t == 0) svalid = valid[i];
  __syncthreads();

  for (int e = t; e < NB * CHID; e += MLP_T) {
    int n = e >> 6, kk = e & 63;
    float a = sb1[kk] + srel[n][0] * sW1[kk] + srel[n][1] * sW1[64 + kk] + srel[n][2] * sW1[128 + kk];
    sh1[n][kk] = fmaxf(a, 0.0f);
  }
  __syncthreads();

  const int vmask = svalid;
  const float bb = b2[t];
  float m = 0.0f;
  bool any = false;
  for (int n = 0; n < NB; ++n) {
    if (vmask & (1 << n)) {
      float acc = bb;
      for (int kk = 0; kk < CHID; ++kk) acc += sh1[n][kk] * sW2[kk * COUT + t];
      m = any ? fmaxf(m, acc) : acc;
      any = true;
    }
  }
  out[i * COUT + t] = any ? m : 0.0f;
}

// ======================= launch =======================
extern "C" void kernel_launch(void* const* d_in, const int* in_sizes, int n_in,
                              void* d_out, int out_size, void* d_ws, size_t ws_size,
                              hipStream_t stream) {
  (void)in_sizes; (void)n_in; (void)out_size; (void)ws_size;
  const float* pos = (const float*)d_in[0];
  const float* W1 = (const float*)d_in[2];
  const float* b1 = (const float*)d_in[3];
  const float* W2 = (const float*)d_in[4];
  const float* b2 = (const float*)d_in[5];
  float* out = (float*)d_out;

  char* ws = (char*)d_ws;
  int*   idx   = (int*)ws;                 ws += (size_t)N_S * 4;          // 32 KB
  int*   src   = (int*)ws;                 ws += (size_t)N_S * NB * 4;     // 320 KB
  int*   valid = (int*)ws;                 ws += (size_t)N_S * 4;          // 32 KB
  float* xs    = (float*)ws;               ws += (size_t)N_PTS * 4;        // 64 KB
  float* ys    = (float*)ws;               ws += (size_t)N_PTS * 4;
  float* zs    = (float*)ws;               ws += (size_t)N_PTS * 4;
  int*   oid   = (int*)ws;                 ws += (size_t)N_PTS * 4;
  // sort temporaries alias the src region (sort completes before knn writes src)
  int* cellid = src;                 // N_PTS ints = 64 KB  (src region is 320 KB)
  int* hist   = src + N_PTS;         // NCELL ints = 16 KB
  int* basebuf= src + N_PTS + NCELL; // NCELL ints = 16 KB

  zero_hist<<<NCELL / 256, 256, 0, stream>>>(hist);
  cell_kernel<<<N_PTS / 256, 256, 0, stream>>>(pos, cellid, hist);
  scan_kernel<<<1, 1024, 0, stream>>>(hist, basebuf);
  scatter_kernel<<<N_PTS / 256, 256, 0, stream>>>(pos, cellid, basebuf, xs, ys, zs, oid);
  fps_kernel<<<1, FPS_T, 0, stream>>>(pos, xs, ys, zs, oid, idx);
  {
    int count = (N_PTS - N_S) * COUT / 4;
    zero_tail<<<(count + 255) / 256, 256, 0, stream>>>((float4*)(out + (size_t)N_S * COUT), count);
  }
  knn_kernel<<<N_S / 32, KNN_T, 0, stream>>>(pos, idx, src, valid);
  mlp_kernel<<<N_S, MLP_T, 0, stream>>>(pos, src, valid, W1, b1, W2, b2, out);
}

// Round 2
// 8002.701 us; speedup vs baseline: 1.2670x; 1.2268x over previous
//
#include <hip/hip_runtime.h>

typedef unsigned int u32;
typedef unsigned long long u64;
typedef float f32x2 __attribute__((ext_vector_type(2)));

#define N_PTS 16384
#define N_S   8192
#define NB    10
#define CHID  64
#define COUT  128
#define R2    0.0625f
#define NCELL 4096

// ======================= sort: morton counting sort =======================
__global__ void zero_hist(int* __restrict__ hist) {
  hist[blockIdx.x * 256 + threadIdx.x] = 0;
}

__device__ __forceinline__ u32 spread3(u32 v) {  // 4 bits -> every 3rd bit
  return (v & 1u) | ((v & 2u) << 2) | ((v & 4u) << 4) | ((v & 8u) << 6);
}

__global__ void cell_kernel(const float* __restrict__ pos, int* __restrict__ cellid,
                            int* __restrict__ hist) {
  int i = blockIdx.x * 256 + threadIdx.x;
  float x = pos[3 * i], y = pos[3 * i + 1], z = pos[3 * i + 2];
  u32 ix = (u32)(x * 16.0f); if (ix > 15u) ix = 15u;
  u32 iy = (u32)(y * 16.0f); if (iy > 15u) iy = 15u;
  u32 iz = (u32)(z * 16.0f); if (iz > 15u) iz = 15u;
  u32 c = spread3(ix) | (spread3(iy) << 1) | (spread3(iz) << 2);
  cellid[i] = (int)c;
  atomicAdd(&hist[c], 1);
}

__global__ __launch_bounds__(1024) void scan_kernel(const int* __restrict__ hist,
                                                    int* __restrict__ base) {
  __shared__ int sp[1024];
  int t = threadIdx.x;
  int h0 = hist[4 * t], h1 = hist[4 * t + 1], h2 = hist[4 * t + 2], h3 = hist[4 * t + 3];
  int s = h0 + h1 + h2 + h3;
  int acc = s;
  sp[t] = s;
  __syncthreads();
  for (int off = 1; off < 1024; off <<= 1) {
    int v = (t >= off) ? sp[t - off] : 0;
    __syncthreads();
    acc += v;
    sp[t] = acc;
    __syncthreads();
  }
  int excl = acc - s;
  base[4 * t + 0] = excl;
  base[4 * t + 1] = excl + h0;
  base[4 * t + 2] = excl + h0 + h1;
  base[4 * t + 3] = excl + h0 + h1 + h2;
}

__global__ void scatter_kernel(const float* __restrict__ pos, const int* __restrict__ cellid,
                               int* __restrict__ base, float* __restrict__ xs,
                               float* __restrict__ ys, float* __restrict__ zs,
                               int* __restrict__ oid) {
  int i = blockIdx.x * 256 + threadIdx.x;
  int c = cellid[i];
  int d = atomicAdd(&base[c], 1);
  xs[d] = pos[3 * i]; ys[d] = pos[3 * i + 1]; zs[d] = pos[3 * i + 2];
  oid[d] = i;
}

// ======================= FPS: R19 (from R18 @ 8.99 ms) ======================
// R18 post-mortem: body-VALU cut (220->144 inst) gave only -2% -> fps is
// SERIAL-CHAIN bound (~2630 cyc/iter), not issue-bound. R19 removes chain
// links, keeping arithmetic/key semantics bit-identical:
//  - y,z in REGISTERS: body is pure VALU (no LDS latency on straggler path;
//    -256 LDS issues/iter early phase). LDS keeps ONE point-indexed (y,z)
//    copy, written once, for the uniform center fetch (1 b64 read, was 2).
//  - block combine via LDS atomicMax(u64) (ds_max_u64): replaces 16-slot
//    publish + post-barrier ds_read + 4-step dpp/max_f64 chain + forward
//    branch. wklast register carries a pruned wave's still-valid entry
//    (md monotone) -> single uniform atomic site per wave.
//  - 3-slot rotation makes slot reset race-free with ONE barrier/iter:
//    iter k maxes into g[k%3]; t0 zeroes g[(k+2)%3] post-barrier (last
//    readers separated by barrier k, next writers by barrier k+1).
// Unchanged: per-op-exact pk math, prune, 6-step dpp wave reduce, key layout.
#define FPS_T 1024
#define PPT   16

#define PT_LIST(OP) OP(0) OP(1) OP(2) OP(3) OP(4) OP(5) OP(6) OP(7) \
                    OP(8) OP(9) OP(10) OP(11) OP(12) OP(13) OP(14) OP(15)
// OP(G, J0,J1,J2,J3, PA,PB): float4 group G covers points 4G..4G+3, pairs PA=2G, PB=2G+1
#define G4_LIST(OP) OP(0,0,1,2,3,0,1)   OP(1,4,5,6,7,2,3) \
                    OP(2,8,9,10,11,4,5) OP(3,12,13,14,15,6,7)
#define PR_LIST(OP) OP(0) OP(1) OP(2) OP(3) OP(4) OP(5) OP(6) OP(7)

// u64 max via positive-double max (keys < 2^60 -> exponent never all-ones, no
// NaN/inf patterns; positive doubles order == bit order).
__device__ __forceinline__ u64 u64fmax(u64 a, u64 b) {
  double ad = __longlong_as_double((long long)a);
  double bd = __longlong_as_double((long long)b);
  return (u64)(long long)__double_as_longlong(fmax(ad, bd));
}

template <int CTRL, int RM>
__device__ __forceinline__ u64 dppmax(u64 cur) {
  int slo = __builtin_amdgcn_update_dpp(0, (int)(u32)cur, CTRL, RM, 0xf, false);
  int shi = __builtin_amdgcn_update_dpp(0, (int)(u32)(cur >> 32), CTRL, RM, 0xf, false);
  u64 o = ((u64)(u32)shi << 32) | (u32)slo;
  return u64fmax(o, cur);
}

// packed 2xf32 ops (VOP3P, gfx90a+). IEEE RNE per element, no contraction
// possible (opaque asm), denorm mode identical to scalar VALU.
__device__ __forceinline__ f32x2 pk_add(f32x2 a, f32x2 b) {
  f32x2 d;
  asm("v_pk_add_f32 %0, %1, %2" : "=v"(d) : "v"(a), "v"(b));
  return d;
}
__device__ __forceinline__ f32x2 pk_mul(f32x2 a, f32x2 b) {
  f32x2 d;
  asm("v_pk_mul_f32 %0, %1, %2" : "=v"(d) : "v"(a), "v"(b));
  return d;
}

__global__ __launch_bounds__(FPS_T, 4)
void fps_kernel(const float* __restrict__ pos,
                const float* __restrict__ xs,
                const float* __restrict__ ys,
                const float* __restrict__ zs,
                const int* __restrict__ oidv,
                int* __restrict__ idx_out) {
  __shared__ float2 s_yz[PPT * FPS_T];       // [j][t] (y,z) per point: 128 KB (center fetch only)
  __shared__ u64    s_g[3];                  // rotating global-max slots
  const int t = threadIdx.x;
  const int base0 = t * PPT;
  const float4* __restrict__ xv = (const float4*)(xs + base0);
  const float4* __restrict__ yv = (const float4*)(ys + base0);
  const float4* __restrict__ zv = (const float4*)(zs + base0);
  const int4*   __restrict__ ov = (const int4*)(oidv + base0);

  // ---- per-point register state: md, x/y/z pairs, key low-word constants
#define DECLP(J) float md##J;
  PT_LIST(DECLP)
#undef DECLP
#define DECLC(J) u32 C##J;
  PT_LIST(DECLC)
#undef DECLC
#define DECLX(P) f32x2 X##P; f32x2 Y##P; f32x2 Z##P;
  PR_LIST(DECLX)
#undef DECLX

  // lane-private chunk bbox lives in registers (constant after init)
  float bnx = 3.4e38f, bxx = -3.4e38f, bny = 3.4e38f, bxy = -3.4e38f,
        bnz = 3.4e38f, bxz = -3.4e38f;

#define INIT4(G, J0, J1, J2, J3, PA, PB) { \
    float4 vx = xv[G], vy = yv[G], vz = zv[G]; int4 vo = ov[G]; \
    md##J0 = 3.402823466e38f; md##J1 = 3.402823466e38f; \
    md##J2 = 3.402823466e38f; md##J3 = 3.402823466e38f; \
    X##PA.x = vx.x; X##PA.y = vx.y; X##PB.x = vx.z; X##PB.y = vx.w; \
    Y##PA.x = vy.x; Y##PA.y = vy.y; Y##PB.x = vy.z; Y##PB.y = vy.w; \
    Z##PA.x = vz.x; Z##PA.y = vz.y; Z##PB.x = vz.z; Z##PB.y = vz.w; \
    s_yz[J0 * FPS_T + t] = make_float2(vy.x, vz.x); \
    s_yz[J1 * FPS_T + t] = make_float2(vy.y, vz.y); \
    s_yz[J2 * FPS_T + t] = make_float2(vy.z, vz.z); \
    s_yz[J3 * FPS_T + t] = make_float2(vy.w, vz.w); \
    C##J0 = ((16383u - (u32)vo.x) << 14) | (u32)(base0 + J0); \
    C##J1 = ((16383u - (u32)vo.y) << 14) | (u32)(base0 + J1); \
    C##J2 = ((16383u - (u32)vo.z) << 14) | (u32)(base0 + J2); \
    C##J3 = ((16383u - (u32)vo.w) << 14) | (u32)(base0 + J3); \
    bnx = fminf(bnx, fminf(fminf(vx.x, vx.y), fminf(vx.z, vx.w))); \
    bxx = fmaxf(bxx, fmaxf(fmaxf(vx.x, vx.y), fmaxf(vx.z, vx.w))); \
    bny = fminf(bny, fminf(fminf(vy.x, vy.y), fminf(vy.z, vy.w))); \
    bxy = fmaxf(bxy, fmaxf(fmaxf(vy.x, vy.y), fmaxf(vy.z, vy.w))); \
    bnz = fminf(bnz, fminf(fminf(vz.x, vz.y), fminf(vz.z, vz.w))); \
    bxz = fmaxf(bxz, fmaxf(fmaxf(vz.x, vz.y), fmaxf(vz.z, vz.w))); }
  G4_LIST(INIT4)
#undef INIT4

  // key = md_bits<<28 | (16383-oid)<<14 | sidx (60 bits). md >= 0 -> float order
  // == bit order. Lex max == numpy argmax (max md, tie -> min oid); sidx trails.
  u64 ckey = 0;
  u64 wklast = 0;                       // lane63: this wave's last published wave-max
  float cmaxf = 3.402823466e38f;        // forces all-active first iteration
  float cx = pos[0], cy = pos[1], cz = pos[2];
  if (t == 0) idx_out[0] = 0;
  if (t < 2) s_g[t] = 0;                // slot 2 zeroed by t0 after iter-0 barrier
  __syncthreads();

  int p = 0;                            // k % 3
  for (int k = 0; k < N_S - 1; ++k) {
    // ---- prune: bbox lower bound vs chunk max-min-dist. Skip-safe: if
    // 0.99*lb2 >= cmaxf no md in this chunk can decrease (1% margin >> fp32
    // rounding of 3-term sums) -> chunk state exactly unchanged.
    float dxl = fmaxf(fmaxf(bnx - cx, cx - bxx), 0.0f);
    float dyl = fmaxf(fmaxf(bny - cy, cy - bxy), 0.0f);
    float dzl = fmaxf(fmaxf(bnz - cz, cz - bxz), 0.0f);
    float lb2 = dxl * dxl + dyl * dyl + dzl * dzl;
    bool act = (0.99f * lb2 < cmaxf);

    if (__ballot(act)) {
      if (act) {
        f32x2 ncx2; ncx2.x = -cx; ncx2.y = -cx;
        f32x2 ncy2; ncy2.x = -cy; ncy2.y = -cy;
        f32x2 ncz2; ncz2.x = -cz; ncz2.y = -cz;
        u64 bkA = 0, bkB = 0;   // even/odd accumulators: halves the dep chain
        // exact numpy arithmetic per element: x+(-c) == x-c (negation exact),
        // pk mul/add are per-op RNE, association (dx2+dy2)+dz2 preserved.
#define UPDP(P, J0, J1) { \
        f32x2 dx2 = pk_add(X##P, ncx2); \
        f32x2 dy2 = pk_add(Y##P, ncy2); \
        f32x2 dz2 = pk_add(Z##P, ncz2); \
        f32x2 sq = pk_add(pk_mul(dx2, dx2), pk_mul(dy2, dy2)); \
        f32x2 d2 = pk_add(sq, pk_mul(dz2, dz2)); \
        float m0 = fminf(md##J0, d2.x); md##J0 = m0; \
        u32 mb0 = __float_as_uint(m0); \
        bkA = u64fmax(bkA, ((u64)(mb0 >> 4) << 32) | ((mb0 << 28) | C##J0)); \
        float m1 = fminf(md##J1, d2.y); md##J1 = m1; \
        u32 mb1 = __float_as_uint(m1); \
        bkB = u64fmax(bkB, ((u64)(mb1 >> 4) << 32) | ((mb1 << 28) | C##J1)); }
        UPDP(0, 0, 1)  UPDP(1, 2, 3)  UPDP(2, 4, 5)  UPDP(3, 6, 7)
        UPDP(4, 8, 9)  UPDP(5, 10, 11) UPDP(6, 12, 13) UPDP(7, 14, 15)
#undef UPDP
        ckey = u64fmax(bkA, bkB);
        cmaxf = __uint_as_float((u32)(ckey >> 28));
      }
      // wave64 max via DPP (row_shr scan + row broadcasts): lane 63 = wave max.
      // Inactive lanes carry their old (still-valid) ckey.
      u64 wk = ckey;
      wk = dppmax<0x111, 0xf>(wk);   // row_shr:1
      wk = dppmax<0x112, 0xf>(wk);   // row_shr:2
      wk = dppmax<0x114, 0xf>(wk);   // row_shr:4
      wk = dppmax<0x118, 0xf>(wk);   // row_shr:8
      wk = dppmax<0x142, 0xa>(wk);   // row_bcast:15 -> rows 1,3
      wk = dppmax<0x143, 0xc>(wk);   // row_bcast:31 -> rows 2,3
      wklast = wk;                   // lane63's value = wave max (others unused)
    }
    // single uniform combine site: active waves publish fresh max, pruned
    // waves republish wklast (still exact: their mds are unchanged, md is
    // monotone non-increasing). max is commutative -> order-independent.
    if ((t & 63) == 63) atomicMax((unsigned long long*)&s_g[p], wklast);
    __syncthreads();

    u64 gmax = s_g[p];                 // same-address broadcast read
    // zero the slot used at k+2: its last readers were pre-barrier(k) [at
    // k-1's tail], its next writers are post-barrier(k+1). Race-free.
    int zslot = (p == 0) ? 2 : p - 1;
    if (t == 0) s_g[zslot] = 0;
    int sidx = (int)(gmax & 16383u);
    if (t == 0) idx_out[k + 1] = 16383 - (int)((gmax >> 14) & 16383u);
    // next center: cx via load from L1/L2-resident xs; cy,cz via ONE uniform
    // broadcast b64 read from the point's LDS cell.
    int cell = (sidx & (PPT - 1)) * FPS_T + (sidx >> 4);
    cx = xs[sidx];
    float2 yz = s_yz[cell];
    cy = yz.x;
    cz = yz.y;
    p = (p == 2) ? 0 : p + 1;
  }
}

// ======================= zero the tail rows [N_S, N_PTS) =======================
__global__ void zero_tail(float4* __restrict__ outv, int count) {
  int i = blockIdx.x * blockDim.x + threadIdx.x;
  if (i < count) outv[i] = make_float4(0.f, 0.f, 0.f, 0.f);
}

// ======================= kNN: 8-way split + exact lex merge =======================
#define KNN_T  256   // 32 centers x 8 splits
#define KTILE  1024

__global__ __launch_bounds__(KNN_T) void knn_kernel(const float* __restrict__ pos,
                                                    const int* __restrict__ fps_idx,
                                                    int* __restrict__ src_out,
                                                    int* __restrict__ valid_out) {
  __shared__ float sx[KTILE], sy[KTILE], sz[KTILE];
  __shared__ float spd[32][8][NB];
  __shared__ int   spi[32][8][NB];
  const int t = threadIdx.x;
  const int sp = t >> 5;
  const int cl = t & 31;
  const int i = blockIdx.x * 32 + cl;
  const int ci = fps_idx[i];
  const float cx = pos[3 * ci], cy = pos[3 * ci + 1], cz = pos[3 * ci + 2];
  float nd[NB]; int ni[NB];
#pragma unroll
  for (int q = 0; q < NB; ++q) { nd[q] = 3.402823466e38f; ni[q] = 0x7fffffff; }

  for (int base = 0; base < N_PTS; base += KTILE) {
    __syncthreads();
    for (int j = t; j < KTILE; j += KNN_T) {
      int pnt = base + j;
      sx[j] = pos[3 * pnt]; sy[j] = pos[3 * pnt + 1]; sz[j] = pos[3 * pnt + 2];
    }
    __syncthreads();
    for (int j = sp; j < KTILE; j += 8) {
      float dx = __fsub_rn(cx, sx[j]);
      float dy = __fsub_rn(cy, sy[j]);
      float dz = __fsub_rn(cz, sz[j]);
      float d2 = __fadd_rn(__fadd_rn(__fmul_rn(dx, dx), __fmul_rn(dy, dy)), __fmul_rn(dz, dz));
      if (d2 < nd[NB - 1]) {
        float cd = d2; int cp = base + j;
#pragma unroll
        for (int q = 0; q < NB; ++q) {
          bool sw = (cd < nd[q]) || (cd == nd[q] && cp < ni[q]);
          if (sw) { float td = nd[q]; int tp = ni[q]; nd[q] = cd; ni[q] = cp; cd = td; cp = tp; }
        }
      }
    }
  }
#pragma unroll
  for (int q = 0; q < NB; ++q) { spd[cl][sp][q] = nd[q]; spi[cl][sp][q] = ni[q]; }
  __syncthreads();
  if (sp == 0) {
    int cur[8];
#pragma unroll
    for (int s = 0; s < 8; ++s) cur[s] = 0;
    int vb = 0;
    for (int q = 0; q < NB; ++q) {
      float bd = 3.402823466e38f; int bi = 0x7fffffff; int bsl = 0;
#pragma unroll
      for (int s = 0; s < 8; ++s) {
        float d = spd[cl][s][cur[s]]; int id = spi[cl][s][cur[s]];
        if (d < bd || (d == bd && id < bi)) { bd = d; bi = id; bsl = s; }
      }
#pragma unroll
      for (int s = 0; s < 8; ++s) cur[s] += (s == bsl) ? 1 : 0;
      src_out[i * NB + q] = bi;
      if (bd <= R2) vb |= (1 << q);
    }
    valid_out[i] = vb;
  }
}

// ======================= MLP + masked max-pool =======================
#define MLP_T 128

__global__ __launch_bounds__(MLP_T) void mlp_kernel(const float* __restrict__ pos,
                                                    const int* __restrict__ src,
                                                    const int* __restrict__ valid,
                                                    const float* __restrict__ W1,
                                                    const float* __restrict__ b1,
                                                    const float* __restrict__ W2,
                                                    const float* __restrict__ b2,
                                                    float* __restrict__ out) {
  __shared__ float sW2[CHID * COUT];
  __shared__ float sW1[3 * CHID];
  __shared__ float sb1[CHID];
  __shared__ float sh1[NB][CHID];
  __shared__ float srel[NB][3];
  __shared__ int   svalid;
  const int t = threadIdx.x;
  const int i = blockIdx.x;

  for (int e = t; e < CHID * COUT; e += MLP_T) sW2[e] = W2[e];
  for (int e = t; e < 3 * CHID; e += MLP_T) sW1[e] = W1[e];
  if (t < CHID) sb1[t] = b1[t];
  if (t < NB) {
    int s = src[i * NB + t];
    // NOTE: reference subtracts pos_i = pos[:s] (row i), NOT the sampled center
    srel[t][0] = pos[3 * s + 0] - pos[3 * i + 0];
    srel[t][1] = pos[3 * s + 1] - pos[3 * i + 1];
    srel[t][2] = pos[3 * s + 2] - pos[3 * i + 2];
  }
  if (t == 0) svalid = valid[i];
  __syncthreads();

  for (int e = t; e < NB * CHID; e += MLP_T) {
    int n = e >> 6, kk = e & 63;
    float a = sb1[kk] + srel[n][0] * sW1[kk] + srel[n][1] * sW1[64 + kk] + srel[n][2] * sW1[128 + kk];
    sh1[n][kk] = fmaxf(a, 0.0f);
  }
  __syncthreads();

  const int vmask = svalid;
  const float bb = b2[t];
  float m = 0.0f;
  bool any = false;
  for (int n = 0; n < NB; ++n) {
    if (vmask & (1 << n)) {
      float acc = bb;
      for (int kk = 0; kk < CHID; ++kk) acc += sh1[n][kk] * sW2[kk * COUT + t];
      m = any ? fmaxf(m, acc) : acc;
      any = true;
    }
  }
  out[i * COUT + t] = any ? m : 0.0f;
}

// ======================= launch =======================
extern "C" void kernel_launch(void* const* d_in, const int* in_sizes, int n_in,
                              void* d_out, int out_size, void* d_ws, size_t ws_size,
                              hipStream_t stream) {
  (void)in_sizes; (void)n_in; (void)out_size; (void)ws_size;
  const float* pos = (const float*)d_in[0];
  const float* W1 = (const float*)d_in[2];
  const float* b1 = (const float*)d_in[3];
  const float* W2 = (const float*)d_in[4];
  const float* b2 = (const float*)d_in[5];
  float* out = (float*)d_out;

  char* ws = (char*)d_ws;
  int*   idx   = (int*)ws;                 ws += (size_t)N_S * 4;          // 32 KB
  int*   src   = (int*)ws;                 ws += (size_t)N_S * NB * 4;     // 320 KB
  int*   valid = (int*)ws;                 ws += (size_t)N_S * 4;          // 32 KB
  float* xs    = (float*)ws;               ws += (size_t)N_PTS * 4;        // 64 KB
  float* ys    = (float*)ws;               ws += (size_t)N_PTS * 4;
  float* zs    = (float*)ws;               ws += (size_t)N_PTS * 4;
  int*   oid   = (int*)ws;                 ws += (size_t)N_PTS * 4;
  // sort temporaries alias the src region (sort completes before knn writes src)
  int* cellid = src;                 // N_PTS ints = 64 KB  (src region is 320 KB)
  int* hist   = src + N_PTS;         // NCELL ints = 16 KB
  int* basebuf= src + N_PTS + NCELL; // NCELL ints = 16 KB

  zero_hist<<<NCELL / 256, 256, 0, stream>>>(hist);
  cell_kernel<<<N_PTS / 256, 256, 0, stream>>>(pos, cellid, hist);
  scan_kernel<<<1, 1024, 0, stream>>>(hist, basebuf);
  scatter_kernel<<<N_PTS / 256, 256, 0, stream>>>(pos, cellid, basebuf, xs, ys, zs, oid);
  fps_kernel<<<1, FPS_T, 0, stream>>>(pos, xs, ys, zs, oid, idx);
  {
    int count = (N_PTS - N_S) * COUT / 4;
    zero_tail<<<(count + 255) / 256, 256, 0, stream>>>((float4*)(out + (size_t)N_S * COUT), count);
  }
  knn_kernel<<<N_S / 32, KNN_T, 0, stream>>>(pos, idx, src, valid);
  mlp_kernel<<<N_S, MLP_T, 0, stream>>>(pos, src, valid, W1, b1, W2, b2, out);
}

// Round 3
// 7772.660 us; speedup vs baseline: 1.3045x; 1.0296x over previous
//
#include <hip/hip_runtime.h>

typedef unsigned int u32;
typedef unsigned long long u64;
typedef float f32x2 __attribute__((ext_vector_type(2)));

#define N_PTS 16384
#define N_S   8192
#define NB    10
#define CHID  64
#define COUT  128
#define R2    0.0625f
#define NCELL 4096

// ======================= sort: morton counting sort =======================
__global__ void zero_hist(int* __restrict__ hist) {
  hist[blockIdx.x * 256 + threadIdx.x] = 0;
}

__device__ __forceinline__ u32 spread3(u32 v) {  // 4 bits -> every 3rd bit
  return (v & 1u) | ((v & 2u) << 2) | ((v & 4u) << 4) | ((v & 8u) << 6);
}

__global__ void cell_kernel(const float* __restrict__ pos, int* __restrict__ cellid,
                            int* __restrict__ hist) {
  int i = blockIdx.x * 256 + threadIdx.x;
  float x = pos[3 * i], y = pos[3 * i + 1], z = pos[3 * i + 2];
  u32 ix = (u32)(x * 16.0f); if (ix > 15u) ix = 15u;
  u32 iy = (u32)(y * 16.0f); if (iy > 15u) iy = 15u;
  u32 iz = (u32)(z * 16.0f); if (iz > 15u) iz = 15u;
  u32 c = spread3(ix) | (spread3(iy) << 1) | (spread3(iz) << 2);
  cellid[i] = (int)c;
  atomicAdd(&hist[c], 1);
}

__global__ __launch_bounds__(1024) void scan_kernel(const int* __restrict__ hist,
                                                    int* __restrict__ base) {
  __shared__ int sp[1024];
  int t = threadIdx.x;
  int h0 = hist[4 * t], h1 = hist[4 * t + 1], h2 = hist[4 * t + 2], h3 = hist[4 * t + 3];
  int s = h0 + h1 + h2 + h3;
  int acc = s;
  sp[t] = s;
  __syncthreads();
  for (int off = 1; off < 1024; off <<= 1) {
    int v = (t >= off) ? sp[t - off] : 0;
    __syncthreads();
    acc += v;
    sp[t] = acc;
    __syncthreads();
  }
  int excl = acc - s;
  base[4 * t + 0] = excl;
  base[4 * t + 1] = excl + h0;
  base[4 * t + 2] = excl + h0 + h1;
  base[4 * t + 3] = excl + h0 + h1 + h2;
}

__global__ void scatter_kernel(const float* __restrict__ pos, const int* __restrict__ cellid,
                               int* __restrict__ base, float* __restrict__ xs,
                               float* __restrict__ ys, float* __restrict__ zs,
                               int* __restrict__ oid) {
  int i = blockIdx.x * 256 + threadIdx.x;
  int c = cellid[i];
  int d = atomicAdd(&base[c], 1);
  xs[d] = pos[3 * i]; ys[d] = pos[3 * i + 1]; zs[d] = pos[3 * i + 2];
  oid[d] = i;
}

// ======================= FPS: R20 (from R19 @ 7.19 ms) ======================
// R19 post-mortem: chain cuts bought exactly their latency (-528 cy/iter).
// Remaining 2107 cy/iter >> identified chain (~900). R20 hypothesis: the
// 16 same-address ds_max_u64 ops serialize in the LDS pipe; the last wave's
// lgkmcnt(0)-before-barrier inherits ~15*theta -> ~1000 cy of the gap.
// Fix: 4 atomic sites (wave wv -> site wv&3, serialization depth 4), combine
// post-barrier with two broadcast ds_read_b128 + 3 v_max_f64 (max is
// commutative -> bit-identical result). Slot rotation proof unchanged; 4 u64
// zeroed per rotation by lanes t<4.
// Unchanged: pk body, prune, dpp wave reduce, key semantics.
#define FPS_T 1024
#define PPT   16

#define PT_LIST(OP) OP(0) OP(1) OP(2) OP(3) OP(4) OP(5) OP(6) OP(7) \
                    OP(8) OP(9) OP(10) OP(11) OP(12) OP(13) OP(14) OP(15)
// OP(G, J0,J1,J2,J3, PA,PB): float4 group G covers points 4G..4G+3, pairs PA=2G, PB=2G+1
#define G4_LIST(OP) OP(0,0,1,2,3,0,1)   OP(1,4,5,6,7,2,3) \
                    OP(2,8,9,10,11,4,5) OP(3,12,13,14,15,6,7)
#define PR_LIST(OP) OP(0) OP(1) OP(2) OP(3) OP(4) OP(5) OP(6) OP(7)

// u64 max via positive-double max (keys < 2^60 -> exponent never all-ones, no
// NaN/inf patterns; positive doubles order == bit order).
__device__ __forceinline__ u64 u64fmax(u64 a, u64 b) {
  double ad = __longlong_as_double((long long)a);
  double bd = __longlong_as_double((long long)b);
  return (u64)(long long)__double_as_longlong(fmax(ad, bd));
}

template <int CTRL, int RM>
__device__ __forceinline__ u64 dppmax(u64 cur) {
  int slo = __builtin_amdgcn_update_dpp(0, (int)(u32)cur, CTRL, RM, 0xf, false);
  int shi = __builtin_amdgcn_update_dpp(0, (int)(u32)(cur >> 32), CTRL, RM, 0xf, false);
  u64 o = ((u64)(u32)shi << 32) | (u32)slo;
  return u64fmax(o, cur);
}

// packed 2xf32 ops (VOP3P, gfx90a+). IEEE RNE per element, no contraction
// possible (opaque asm), denorm mode identical to scalar VALU.
__device__ __forceinline__ f32x2 pk_add(f32x2 a, f32x2 b) {
  f32x2 d;
  asm("v_pk_add_f32 %0, %1, %2" : "=v"(d) : "v"(a), "v"(b));
  return d;
}
__device__ __forceinline__ f32x2 pk_mul(f32x2 a, f32x2 b) {
  f32x2 d;
  asm("v_pk_mul_f32 %0, %1, %2" : "=v"(d) : "v"(a), "v"(b));
  return d;
}

__global__ __launch_bounds__(FPS_T, 4)
void fps_kernel(const float* __restrict__ pos,
                const float* __restrict__ xs,
                const float* __restrict__ ys,
                const float* __restrict__ zs,
                const int* __restrict__ oidv,
                int* __restrict__ idx_out) {
  __shared__ float2 s_yz[PPT * FPS_T];          // [j][t] (y,z): 128 KB (center fetch only)
  __shared__ __align__(32) u64 s_g[3][4];       // rotating 4-site global-max slots
  const int t = threadIdx.x;
  const int wv = t >> 6;
  const int base0 = t * PPT;
  const float4* __restrict__ xv = (const float4*)(xs + base0);
  const float4* __restrict__ yv = (const float4*)(ys + base0);
  const float4* __restrict__ zv = (const float4*)(zs + base0);
  const int4*   __restrict__ ov = (const int4*)(oidv + base0);

  // ---- per-point register state: md, x/y/z pairs, key low-word constants
#define DECLP(J) float md##J;
  PT_LIST(DECLP)
#undef DECLP
#define DECLC(J) u32 C##J;
  PT_LIST(DECLC)
#undef DECLC
#define DECLX(P) f32x2 X##P; f32x2 Y##P; f32x2 Z##P;
  PR_LIST(DECLX)
#undef DECLX

  // lane-private chunk bbox lives in registers (constant after init)
  float bnx = 3.4e38f, bxx = -3.4e38f, bny = 3.4e38f, bxy = -3.4e38f,
        bnz = 3.4e38f, bxz = -3.4e38f;

#define INIT4(G, J0, J1, J2, J3, PA, PB) { \
    float4 vx = xv[G], vy = yv[G], vz = zv[G]; int4 vo = ov[G]; \
    md##J0 = 3.402823466e38f; md##J1 = 3.402823466e38f; \
    md##J2 = 3.402823466e38f; md##J3 = 3.402823466e38f; \
    X##PA.x = vx.x; X##PA.y = vx.y; X##PB.x = vx.z; X##PB.y = vx.w; \
    Y##PA.x = vy.x; Y##PA.y = vy.y; Y##PB.x = vy.z; Y##PB.y = vy.w; \
    Z##PA.x = vz.x; Z##PA.y = vz.y; Z##PB.x = vz.z; Z##PB.y = vz.w; \
    s_yz[J0 * FPS_T + t] = make_float2(vy.x, vz.x); \
    s_yz[J1 * FPS_T + t] = make_float2(vy.y, vz.y); \
    s_yz[J2 * FPS_T + t] = make_float2(vy.z, vz.z); \
    s_yz[J3 * FPS_T + t] = make_float2(vy.w, vz.w); \
    C##J0 = ((16383u - (u32)vo.x) << 14) | (u32)(base0 + J0); \
    C##J1 = ((16383u - (u32)vo.y) << 14) | (u32)(base0 + J1); \
    C##J2 = ((16383u - (u32)vo.z) << 14) | (u32)(base0 + J2); \
    C##J3 = ((16383u - (u32)vo.w) << 14) | (u32)(base0 + J3); \
    bnx = fminf(bnx, fminf(fminf(vx.x, vx.y), fminf(vx.z, vx.w))); \
    bxx = fmaxf(bxx, fmaxf(fmaxf(vx.x, vx.y), fmaxf(vx.z, vx.w))); \
    bny = fminf(bny, fminf(fminf(vy.x, vy.y), fminf(vy.z, vy.w))); \
    bxy = fmaxf(bxy, fmaxf(fmaxf(vy.x, vy.y), fmaxf(vy.z, vy.w))); \
    bnz = fminf(bnz, fminf(fminf(vz.x, vz.y), fminf(vz.z, vz.w))); \
    bxz = fmaxf(bxz, fmaxf(fmaxf(vz.x, vz.y), fmaxf(vz.z, vz.w))); }
  G4_LIST(INIT4)
#undef INIT4

  // key = md_bits<<28 | (16383-oid)<<14 | sidx (60 bits). md >= 0 -> float order
  // == bit order. Lex max == numpy argmax (max md, tie -> min oid); sidx trails.
  u64 ckey = 0;
  u64 wklast = 0;                       // lane63: this wave's last published wave-max
  float cmaxf = 3.402823466e38f;        // forces all-active first iteration
  float cx = pos[0], cy = pos[1], cz = pos[2];
  if (t == 0) idx_out[0] = 0;
  if (t < 8) s_g[t >> 2][t & 3] = 0;    // zero phase 0,1 sites; phase 2 zeroed at iter 0
  __syncthreads();

  int p = 0;                            // k % 3
  for (int k = 0; k < N_S - 1; ++k) {
    // ---- prune: bbox lower bound vs chunk max-min-dist. Skip-safe: if
    // 0.99*lb2 >= cmaxf no md in this chunk can decrease (1% margin >> fp32
    // rounding of 3-term sums) -> chunk state exactly unchanged.
    float dxl = fmaxf(fmaxf(bnx - cx, cx - bxx), 0.0f);
    float dyl = fmaxf(fmaxf(bny - cy, cy - bxy), 0.0f);
    float dzl = fmaxf(fmaxf(bnz - cz, cz - bxz), 0.0f);
    float lb2 = dxl * dxl + dyl * dyl + dzl * dzl;
    bool act = (0.99f * lb2 < cmaxf);

    if (__ballot(act)) {
      if (act) {
        f32x2 ncx2; ncx2.x = -cx; ncx2.y = -cx;
        f32x2 ncy2; ncy2.x = -cy; ncy2.y = -cy;
        f32x2 ncz2; ncz2.x = -cz; ncz2.y = -cz;
        u64 bkA = 0, bkB = 0;   // even/odd accumulators: halves the dep chain
        // exact numpy arithmetic per element: x+(-c) == x-c (negation exact),
        // pk mul/add are per-op RNE, association (dx2+dy2)+dz2 preserved.
#define UPDP(P, J0, J1) { \
        f32x2 dx2 = pk_add(X##P, ncx2); \
        f32x2 dy2 = pk_add(Y##P, ncy2); \
        f32x2 dz2 = pk_add(Z##P, ncz2); \
        f32x2 sq = pk_add(pk_mul(dx2, dx2), pk_mul(dy2, dy2)); \
        f32x2 d2 = pk_add(sq, pk_mul(dz2, dz2)); \
        float m0 = fminf(md##J0, d2.x); md##J0 = m0; \
        u32 mb0 = __float_as_uint(m0); \
        bkA = u64fmax(bkA, ((u64)(mb0 >> 4) << 32) | ((mb0 << 28) | C##J0)); \
        float m1 = fminf(md##J1, d2.y); md##J1 = m1; \
        u32 mb1 = __float_as_uint(m1); \
        bkB = u64fmax(bkB, ((u64)(mb1 >> 4) << 32) | ((mb1 << 28) | C##J1)); }
        UPDP(0, 0, 1)  UPDP(1, 2, 3)  UPDP(2, 4, 5)  UPDP(3, 6, 7)
        UPDP(4, 8, 9)  UPDP(5, 10, 11) UPDP(6, 12, 13) UPDP(7, 14, 15)
#undef UPDP
        ckey = u64fmax(bkA, bkB);
        cmaxf = __uint_as_float((u32)(ckey >> 28));
      }
      // wave64 max via DPP (row_shr scan + row broadcasts): lane 63 = wave max.
      // Inactive lanes carry their old (still-valid) ckey.
      u64 wk = ckey;
      wk = dppmax<0x111, 0xf>(wk);   // row_shr:1
      wk = dppmax<0x112, 0xf>(wk);   // row_shr:2
      wk = dppmax<0x114, 0xf>(wk);   // row_shr:4
      wk = dppmax<0x118, 0xf>(wk);   // row_shr:8
      wk = dppmax<0x142, 0xa>(wk);   // row_bcast:15 -> rows 1,3
      wk = dppmax<0x143, 0xc>(wk);   // row_bcast:31 -> rows 2,3
      wklast = wk;                   // lane63's value = wave max (others unused)
    }
    // 4-site combine: active waves publish fresh max, pruned waves republish
    // wklast (still exact: their mds are unchanged, md monotone). Sites get
    // exactly the 4 waves with wv = site (mod 4). Serialization depth 4.
    if ((t & 63) == 63) atomicMax((unsigned long long*)&s_g[p][wv & 3], wklast);
    __syncthreads();

    // two broadcast b128 reads (back-to-back, 2nd latency hidden) + 3-max tree
    ulonglong2 gA = *(const ulonglong2*)&s_g[p][0];
    ulonglong2 gB = *(const ulonglong2*)&s_g[p][2];
    u64 gmax = u64fmax(u64fmax(gA.x, gA.y), u64fmax(gB.x, gB.y));
    // zero the phase used at k+2: its last readers were pre-barrier(k+1), its
    // next writers are post-barrier(k+2). Race-free (same proof as R19).
    int zslot = (p == 0) ? 2 : p - 1;
    if (t < 4) s_g[zslot][t] = 0;
    int sidx = (int)(gmax & 16383u);
    if (t == 0) idx_out[k + 1] = 16383 - (int)((gmax >> 14) & 16383u);
    // next center: cx via load from L1/L2-resident xs; cy,cz via ONE uniform
    // broadcast b64 read from the point's LDS cell.
    int cell = (sidx & (PPT - 1)) * FPS_T + (sidx >> 4);
    cx = xs[sidx];
    float2 yz = s_yz[cell];
    cy = yz.x;
    cz = yz.y;
    p = (p == 2) ? 0 : p + 1;
  }
}

// ======================= zero the tail rows [N_S, N_PTS) =======================
__global__ void zero_tail(float4* __restrict__ outv, int count) {
  int i = blockIdx.x * blockDim.x + threadIdx.x;
  if (i < count) outv[i] = make_float4(0.f, 0.f, 0.f, 0.f);
}

// ======================= kNN: 8-way split + exact lex merge =======================
#define KNN_T  256   // 32 centers x 8 splits
#define KTILE  1024

__global__ __launch_bounds__(KNN_T) void knn_kernel(const float* __restrict__ pos,
                                                    const int* __restrict__ fps_idx,
                                                    int* __restrict__ src_out,
                                                    int* __restrict__ valid_out) {
  __shared__ float sx[KTILE], sy[KTILE], sz[KTILE];
  __shared__ float spd[32][8][NB];
  __shared__ int   spi[32][8][NB];
  const int t = threadIdx.x;
  const int sp = t >> 5;
  const int cl = t & 31;
  const int i = blockIdx.x * 32 + cl;
  const int ci = fps_idx[i];
  const float cx = pos[3 * ci], cy = pos[3 * ci + 1], cz = pos[3 * ci + 2];
  float nd[NB]; int ni[NB];
#pragma unroll
  for (int q = 0; q < NB; ++q) { nd[q] = 3.402823466e38f; ni[q] = 0x7fffffff; }

  for (int base = 0; base < N_PTS; base += KTILE) {
    __syncthreads();
    for (int j = t; j < KTILE; j += KNN_T) {
      int pnt = base + j;
      sx[j] = pos[3 * pnt]; sy[j] = pos[3 * pnt + 1]; sz[j] = pos[3 * pnt + 2];
    }
    __syncthreads();
    for (int j = sp; j < KTILE; j += 8) {
      float dx = __fsub_rn(cx, sx[j]);
      float dy = __fsub_rn(cy, sy[j]);
      float dz = __fsub_rn(cz, sz[j]);
      float d2 = __fadd_rn(__fadd_rn(__fmul_rn(dx, dx), __fmul_rn(dy, dy)), __fmul_rn(dz, dz));
      if (d2 < nd[NB - 1]) {
        float cd = d2; int cp = base + j;
#pragma unroll
        for (int q = 0; q < NB; ++q) {
          bool sw = (cd < nd[q]) || (cd == nd[q] && cp < ni[q]);
          if (sw) { float td = nd[q]; int tp = ni[q]; nd[q] = cd; ni[q] = cp; cd = td; cp = tp; }
        }
      }
    }
  }
#pragma unroll
  for (int q = 0; q < NB; ++q) { spd[cl][sp][q] = nd[q]; spi[cl][sp][q] = ni[q]; }
  __syncthreads();
  if (sp == 0) {
    int cur[8];
#pragma unroll
    for (int s = 0; s < 8; ++s) cur[s] = 0;
    int vb = 0;
    for (int q = 0; q < NB; ++q) {
      float bd = 3.402823466e38f; int bi = 0x7fffffff; int bsl = 0;
#pragma unroll
      for (int s = 0; s < 8; ++s) {
        float d = spd[cl][s][cur[s]]; int id = spi[cl][s][cur[s]];
        if (d < bd || (d == bd && id < bi)) { bd = d; bi = id; bsl = s; }
      }
#pragma unroll
      for (int s = 0; s < 8; ++s) cur[s] += (s == bsl) ? 1 : 0;
      src_out[i * NB + q] = bi;
      if (bd <= R2) vb |= (1 << q);
    }
    valid_out[i] = vb;
  }
}

// ======================= MLP + masked max-pool =======================
#define MLP_T 128

__global__ __launch_bounds__(MLP_T) void mlp_kernel(const float* __restrict__ pos,
                                                    const int* __restrict__ src,
                                                    const int* __restrict__ valid,
                                                    const float* __restrict__ W1,
                                                    const float* __restrict__ b1,
                                                    const float* __restrict__ W2,
                                                    const float* __restrict__ b2,
                                                    float* __restrict__ out) {
  __shared__ float sW2[CHID * COUT];
  __shared__ float sW1[3 * CHID];
  __shared__ float sb1[CHID];
  __shared__ float sh1[NB][CHID];
  __shared__ float srel[NB][3];
  __shared__ int   svalid;
  const int t = threadIdx.x;
  const int i = blockIdx.x;

  for (int e = t; e < CHID * COUT; e += MLP_T) sW2[e] = W2[e];
  for (int e = t; e < 3 * CHID; e += MLP_T) sW1[e] = W1[e];
  if (t < CHID) sb1[t] = b1[t];
  if (t < NB) {
    int s = src[i * NB + t];
    // NOTE: reference subtracts pos_i = pos[:s] (row i), NOT the sampled center
    srel[t][0] = pos[3 * s + 0] - pos[3 * i + 0];
    srel[t][1] = pos[3 * s + 1] - pos[3 * i + 1];
    srel[t][2] = pos[3 * s + 2] - pos[3 * i + 2];
  }
  if (t == 0) svalid = valid[i];
  __syncthreads();

  for (int e = t; e < NB * CHID; e += MLP_T) {
    int n = e >> 6, kk = e & 63;
    float a = sb1[kk] + srel[n][0] * sW1[kk] + srel[n][1] * sW1[64 + kk] + srel[n][2] * sW1[128 + kk];
    sh1[n][kk] = fmaxf(a, 0.0f);
  }
  __syncthreads();

  const int vmask = svalid;
  const float bb = b2[t];
  float m = 0.0f;
  bool any = false;
  for (int n = 0; n < NB; ++n) {
    if (vmask & (1 << n)) {
      float acc = bb;
      for (int kk = 0; kk < CHID; ++kk) acc += sh1[n][kk] * sW2[kk * COUT + t];
      m = any ? fmaxf(m, acc) : acc;
      any = true;
    }
  }
  out[i * COUT + t] = any ? m : 0.0f;
}

// ======================= launch =======================
extern "C" void kernel_launch(void* const* d_in, const int* in_sizes, int n_in,
                              void* d_out, int out_size, void* d_ws, size_t ws_size,
                              hipStream_t stream) {
  (void)in_sizes; (void)n_in; (void)out_size; (void)ws_size;
  const float* pos = (const float*)d_in[0];
  const float* W1 = (const float*)d_in[2];
  const float* b1 = (const float*)d_in[3];
  const float* W2 = (const float*)d_in[4];
  const float* b2 = (const float*)d_in[5];
  float* out = (float*)d_out;

  char* ws = (char*)d_ws;
  int*   idx   = (int*)ws;                 ws += (size_t)N_S * 4;          // 32 KB
  int*   src   = (int*)ws;                 ws += (size_t)N_S * NB * 4;     // 320 KB
  int*   valid = (int*)ws;                 ws += (size_t)N_S * 4;          // 32 KB
  float* xs    = (float*)ws;               ws += (size_t)N_PTS * 4;        // 64 KB
  float* ys    = (float*)ws;               ws += (size_t)N_PTS * 4;
  float* zs    = (float*)ws;               ws += (size_t)N_PTS * 4;
  int*   oid   = (int*)ws;                 ws += (size_t)N_PTS * 4;
  // sort temporaries alias the src region (sort completes before knn writes src)
  int* cellid = src;                 // N_PTS ints = 64 KB  (src region is 320 KB)
  int* hist   = src + N_PTS;         // NCELL ints = 16 KB
  int* basebuf= src + N_PTS + NCELL; // NCELL ints = 16 KB

  zero_hist<<<NCELL / 256, 256, 0, stream>>>(hist);
  cell_kernel<<<N_PTS / 256, 256, 0, stream>>>(pos, cellid, hist);
  scan_kernel<<<1, 1024, 0, stream>>>(hist, basebuf);
  scatter_kernel<<<N_PTS / 256, 256, 0, stream>>>(pos, cellid, basebuf, xs, ys, zs, oid);
  fps_kernel<<<1, FPS_T, 0, stream>>>(pos, xs, ys, zs, oid, idx);
  {
    int count = (N_PTS - N_S) * COUT / 4;
    zero_tail<<<(count + 255) / 256, 256, 0, stream>>>((float4*)(out + (size_t)N_S * COUT), count);
  }
  knn_kernel<<<N_S / 32, KNN_T, 0, stream>>>(pos, idx, src, valid);
  mlp_kernel<<<N_S, MLP_T, 0, stream>>>(pos, src, valid, W1, b1, W2, b2, out);
}